// Round 4
// baseline (672.490 us; speedup 1.0000x reference)
//
#include <hip/hip_runtime.h>

// ---------------------------------------------------------------------------
// Generator head, fused:
//   FC(1024->7056) + Conv2x2'same' folded into one bf16 GEMM
//   (M=8192, N=3136 pad 3200, K=1024, BK=32), K-loop = register-prefetch +
//   LDS double-buffer pipeline (loads in flight across barriers, no vmcnt(0)
//   drain). Epilogue: +bias, LeakyReLU, bf16 store transposed (h2T[n][m]) +
//   fused per-column BN stats. Then BN-apply + local conv1 (with inline BN
//   scale reduce) and local conv2, batch-per-lane (wave-uniform weights).
// ---------------------------------------------------------------------------

#define SLOPE 0.01f

typedef __bf16 bf16x8 __attribute__((ext_vector_type(8)));
typedef float f32x4 __attribute__((ext_vector_type(4)));

__device__ __forceinline__ unsigned short f2bf(float f) {
  union { float f; unsigned int u; } v; v.f = f;
  unsigned int r = v.u + 0x7FFFu + ((v.u >> 16) & 1u);
  return (unsigned short)(r >> 16);
}
__device__ __forceinline__ float bfbits2f(unsigned int bits16) {
  union { unsigned int u; float f; } v; v.u = bits16 << 16;
  return v.f;
}
__device__ __forceinline__ float leaky(float v) { return v >= 0.f ? v : SLOPE * v; }

// ---------------- K0: fused cast-x + weight-fold (one dispatch) ------------
// blocks [0,4096): cast x -> bf16 (8 floats/thread). block 0 zeroes stats.
// blocks [4096,4884): fold conv into fc -> Wc row n = o*196+i*14+j, bf16.
__global__ void k_prep(const float* __restrict__ x, unsigned short* __restrict__ xb,
                       float* __restrict__ stats_col,
                       const float* __restrict__ fc_w, const float* __restrict__ fc_b,
                       const float* __restrict__ conv_w, const float* __restrict__ conv_b,
                       unsigned short* __restrict__ Wc, float* __restrict__ bc) {
  const int t = threadIdx.x;
  if (blockIdx.x < 4096) {
    if (blockIdx.x == 0)
      for (int i = t; i < 6400; i += 256) stats_col[i] = 0.f;
    int gid = blockIdx.x * 256 + t;
    const float4* x4 = (const float4*)x;
    float4 a = x4[gid * 2], b = x4[gid * 2 + 1];
    union { unsigned short s[8]; uint4 v; } o;
    o.s[0] = f2bf(a.x); o.s[1] = f2bf(a.y); o.s[2] = f2bf(a.z); o.s[3] = f2bf(a.w);
    o.s[4] = f2bf(b.x); o.s[5] = f2bf(b.y); o.s[6] = f2bf(b.z); o.s[7] = f2bf(b.w);
    ((uint4*)xb)[gid] = o.v;
    return;
  }
  int bid = blockIdx.x - 4096;          // 0..787
  int kq = bid & 3, blk = bid >> 2;     // 4 k-quarters x 197
  if (blk == 196) {                     // zero pad rows [3136,3200)
    uint4 z = make_uint4(0, 0, 0, 0);
    for (int i = t; i < 64 * 32; i += 256) {
      int r = i >> 5, qq = i & 31;
      *(uint4*)(Wc + (3136 + r) * 1024 + kq * 256 + qq * 8) = z;
    }
    if (kq == 0) for (int i = 3136 + t; i < 3200; i += 256) bc[i] = 0.f;
    return;
  }
  __shared__ float cw[2304];  // 16*36*2*2
  for (int i = t; i < 2304; i += 256) cw[i] = conv_w[i];
  __syncthreads();
  int i0 = blk / 14, j0 = blk - (blk / 14) * 14;
  int k = kq * 256 + t;
  float acc[16];
#pragma unroll
  for (int o = 0; o < 16; o++) acc[o] = 0.f;
  for (int c = 0; c < 36; c++) {
#pragma unroll
    for (int dy = 0; dy < 2; dy++) {
      int ii = i0 + dy; if (ii > 13) continue;
#pragma unroll
      for (int dx = 0; dx < 2; dx++) {
        int jj = j0 + dx; if (jj > 13) continue;
        float f = fc_w[((ii * 14 + jj) * 36 + c) * 1024 + k];
        int kk = dy * 2 + dx;
#pragma unroll
        for (int o = 0; o < 16; o++) acc[o] += cw[(o * 36 + c) * 4 + kk] * f;
      }
    }
  }
#pragma unroll
  for (int o = 0; o < 16; o++)
    Wc[(o * 196 + i0 * 14 + j0) * 1024 + k] = f2bf(acc[o]);
  if (kq == 0 && t < 16) {
    int o = t;
    float b = conv_b[o];
    for (int c = 0; c < 36; c++)
      for (int dy = 0; dy < 2; dy++) {
        int ii = i0 + dy; if (ii > 13) continue;
        for (int dx = 0; dx < 2; dx++) {
          int jj = j0 + dx; if (jj > 13) continue;
          b += cw[(o * 36 + c) * 4 + dy * 2 + dx] * fc_b[(ii * 14 + jj) * 36 + c];
        }
      }
    bc[o * 196 + i0 * 14 + j0] = b;
  }
}

// ------------- K2: bf16 MFMA GEMM, reg-prefetch + LDS double-buffer --------
// C[m][n] = sum_k Xb[m][k]*Wc[n][k]. Tile 128x128, BK=32, 32 pipelined iters:
//   iter j: ds_read frags from buf[j&1]; issue global loads for iter j+2 into
//   reg set[j&1]; 16 MFMA; ds_write buf[(j+1)&1] from set[(j+1)&1]; barrier.
// Loads are waited (fine-grained vmcnt by compiler) only at the NEXT iter's
// ds_write -> one full iteration of latency hiding, no vmcnt(0) drain.
// Prefetch overruns K by 2 iters; reads stay inside d_ws (values unused).
__global__ __launch_bounds__(256, 3) void k_gemm(const unsigned short* __restrict__ Xb,
                                                 const unsigned short* __restrict__ Wcb,
                                                 const float* __restrict__ bc,
                                                 unsigned short* __restrict__ h2,
                                                 float* __restrict__ stats_col) {
  __shared__ __align__(16) char lds[32768];  // buf0 [0,16K): A 8K | B 8K; buf1 [16K,32K)
  const int t = threadIdx.x;
  const int w = t >> 6, lane = t & 63;
  const int quad = lane >> 4, l15 = lane & 15;
  const int lid = blockIdx.x;
  const int m0 = (lid & 63) * 128, n0 = (lid >> 6) * 128;  // y-major (XCD A-banding)
  const int mrow = t & 127, tko = t >> 7;
  const unsigned short* ga = Xb + (m0 + mrow) * 1024 + tko * 8;
  const unsigned short* gb = Wcb + (n0 + mrow) * 1024 + tko * 8;
  char* const wA = lds + tko * 2048 + mrow * 16;  // slot tko; +4096 -> slot tko+2
  const int wm0 = (w >> 1) * 64, wn0 = (w & 1) * 64;

  f32x4 acc[4][4];
#pragma unroll
  for (int a = 0; a < 4; a++)
#pragma unroll
    for (int b = 0; b < 4; b++) acc[a][b] = (f32x4){0.f, 0.f, 0.f, 0.f};

  uint4 ra[2][2], rb[2][2];
  // prologue: iter0 -> set0 -> buf0; iter1 -> set1 (written inside loop j=0)
  ra[0][0] = *(const uint4*)(ga);      ra[0][1] = *(const uint4*)(ga + 16);
  rb[0][0] = *(const uint4*)(gb);      rb[0][1] = *(const uint4*)(gb + 16);
  *(uint4*)(wA)        = ra[0][0];  *(uint4*)(wA + 4096)        = ra[0][1];
  *(uint4*)(wA + 8192) = rb[0][0];  *(uint4*)(wA + 8192 + 4096) = rb[0][1];
  ra[1][0] = *(const uint4*)(ga + 32); ra[1][1] = *(const uint4*)(ga + 48);
  rb[1][0] = *(const uint4*)(gb + 32); rb[1][1] = *(const uint4*)(gb + 48);
  __syncthreads();

#pragma unroll 2
  for (int j = 0; j < 32; j++) {
    const int cur = j & 1, nxt = cur ^ 1;
    const char* rbuf = lds + cur * 16384;
    bf16x8 af[4], bfr[4];
#pragma unroll
    for (int mb = 0; mb < 4; mb++)
      af[mb] = *(const bf16x8*)(rbuf + quad * 2048 + (wm0 + mb * 16 + l15) * 16);
#pragma unroll
    for (int nb = 0; nb < 4; nb++)
      bfr[nb] = *(const bf16x8*)(rbuf + 8192 + quad * 2048 + (wn0 + nb * 16 + l15) * 16);
    // prefetch iter j+2 into set cur (overruns K for j>=30; harmless in-ws reads)
    {
      const int off = (j + 2) * 32;
      ra[cur][0] = *(const uint4*)(ga + off);      ra[cur][1] = *(const uint4*)(ga + off + 16);
      rb[cur][0] = *(const uint4*)(gb + off);      rb[cur][1] = *(const uint4*)(gb + off + 16);
    }
#pragma unroll
    for (int mb = 0; mb < 4; mb++)
#pragma unroll
      for (int nb = 0; nb < 4; nb++)
        acc[mb][nb] = __builtin_amdgcn_mfma_f32_16x16x32_bf16(af[mb], bfr[nb], acc[mb][nb], 0, 0, 0);
    // write iter j+1 (set nxt) into buf nxt
    {
      char* wb_ = lds + nxt * 16384 + tko * 2048 + mrow * 16;
      *(uint4*)(wb_)        = ra[nxt][0];  *(uint4*)(wb_ + 4096)        = ra[nxt][1];
      *(uint4*)(wb_ + 8192) = rb[nxt][0];  *(uint4*)(wb_ + 8192 + 4096) = rb[nxt][1];
    }
    __syncthreads();
  }

#pragma unroll
  for (int nb = 0; nb < 4; nb++) {
    int col = n0 + wn0 + nb * 16 + l15;
    float bias = bc[col];
    float s = 0.f, s2 = 0.f;
    unsigned short* base = h2 + col * 8192 + m0 + wm0 + quad * 4;
#pragma unroll
    for (int mb = 0; mb < 4; mb++) {
      union { unsigned short u[4]; uint2 v; } pk;
#pragma unroll
      for (int r = 0; r < 4; r++) {
        float v = leaky(acc[mb][nb][r] + bias);   // C/D: row=(lane>>4)*4+reg, col=lane&15
        s += v; s2 += v * v;
        pk.u[r] = f2bf(v);
      }
      *(uint2*)(base + mb * 16) = pk.v;           // 8B store, m-contiguous
    }
    s  += __shfl_xor(s, 16, 64);  s  += __shfl_xor(s, 32, 64);
    s2 += __shfl_xor(s2, 16, 64); s2 += __shfl_xor(s2, 32, 64);
    if (quad == 0) {
      atomicAdd(&stats_col[col], s);
      atomicAdd(&stats_col[3200 + col], s2);
    }
  }
}

// -------- K3: BN scale reduce (inline) + BN-apply + local conv1 + leaky ----
// Grid (32 m-windows of 256, 13 y). Batch-per-lane; wave-uniform weights.
__global__ __launch_bounds__(256) void k_tail1(const unsigned short* __restrict__ h2,
                                               const float* __restrict__ stats_col,
                                               const float* __restrict__ gamma,
                                               const float* __restrict__ beta,
                                               const float* __restrict__ lw1,
                                               unsigned short* __restrict__ h4) {
  __shared__ float chs[32];
  __shared__ float sc_s[16], sh_s[16];
  const int t = threadIdx.x;
  if (t < 32) chs[t] = 0.f;
  __syncthreads();
  for (int col = t; col < 3136; col += 256) {
    int o = col / 196;
    atomicAdd(&chs[o], stats_col[col]);
    atomicAdd(&chs[16 + o], stats_col[3200 + col]);
  }
  __syncthreads();
  if (t < 16) {
    const float inv = 1.f / 1605632.f;  // 8192*196
    float mean = chs[t] * inv;
    float var = chs[16 + t] * inv - mean * mean;
    float sc = gamma[t] * rsqrtf(var + 1e-5f);
    sc_s[t] = sc; sh_s[t] = beta[t] - mean * sc;
  }
  __syncthreads();

  const int m = blockIdx.x * 256 + t;
  const int y = blockIdx.y;                     // 0..12
  float acc[6][13];
#pragma unroll
  for (int o = 0; o < 6; o++)
#pragma unroll
    for (int x = 0; x < 13; x++) acc[o][x] = 0.f;

  for (int c = 0; c < 16; c++) {
    float scc = sc_s[c], shc = sh_s[c];
    const unsigned short* p0 = h2 + (c * 196 + y * 14) * 8192 + m;
    float r0[14], r1[14];
#pragma unroll
    for (int x = 0; x < 14; x++) {
      r0[x] = bfbits2f(p0[x * 8192]) * scc + shc;
      r1[x] = bfbits2f(p0[(14 + x) * 8192]) * scc + shc;
    }
#pragma unroll
    for (int o = 0; o < 6; o++) {
      const float* wp = lw1 + (((o * 16 + c) * 13 + y) * 13) * 4;  // uniform -> s_load
#pragma unroll
      for (int x = 0; x < 13; x++)
        acc[o][x] += r0[x] * wp[4 * x] + r0[x + 1] * wp[4 * x + 1] +
                     r1[x] * wp[4 * x + 2] + r1[x + 1] * wp[4 * x + 3];
    }
  }
  unsigned short* q = h4 + y * 13 * 8192 + m;   // row (o*13+y)*13+x
#pragma unroll
  for (int o = 0; o < 6; o++)
#pragma unroll
    for (int x = 0; x < 13; x++)
      q[(o * 169 + x) * 8192] = f2bf(leaky(acc[o][x]));
}

// ------------------------- K4: local conv2 (batch-per-lane) ----------------
__global__ __launch_bounds__(256) void k_tail2(const unsigned short* __restrict__ h4,
                                               const float* __restrict__ lw2,
                                               float* __restrict__ out) {
  const int lane = threadIdx.x & 63, w = threadIdx.x >> 6;
  const int m = blockIdx.x * 64 + lane;
  const int y = blockIdx.y * 4 + w;             // 0..11
  float acc[12];
#pragma unroll
  for (int x = 0; x < 12; x++) acc[x] = 0.f;
  for (int c = 0; c < 6; c++) {
    const unsigned short* p = h4 + (c * 13 + y) * 13 * 8192 + m;
    float r0[13], r1[13];
#pragma unroll
    for (int x = 0; x < 13; x++) {
      r0[x] = bfbits2f(p[x * 8192]);
      r1[x] = bfbits2f(p[(13 + x) * 8192]);
    }
    const float* wp = lw2 + ((c * 12 + y) * 12) * 4;  // uniform -> s_load
#pragma unroll
    for (int x = 0; x < 12; x++)
      acc[x] += r0[x] * wp[4 * x] + r0[x + 1] * wp[4 * x + 1] +
                r1[x] * wp[4 * x + 2] + r1[x + 1] * wp[4 * x + 3];
  }
  float* op = out + m * 144 + y * 12;
#pragma unroll
  for (int x = 0; x < 12; x++) op[x] = acc[x];
}

// ---------------------------------------------------------------------------
extern "C" void kernel_launch(void* const* d_in, const int* in_sizes, int n_in,
                              void* d_out, int out_size, void* d_ws, size_t ws_size,
                              hipStream_t stream) {
  const float* x      = (const float*)d_in[0];
  const float* fc_w   = (const float*)d_in[1];
  const float* fc_b   = (const float*)d_in[2];
  const float* conv_w = (const float*)d_in[3];
  const float* conv_b = (const float*)d_in[4];
  const float* gamma  = (const float*)d_in[5];
  const float* beta   = (const float*)d_in[6];
  const float* lw1    = (const float*)d_in[7];
  const float* lw2    = (const float*)d_in[8];

  char* ws = (char*)d_ws;
  // workspace layout (75.8 MB total)
  unsigned short* Xb        = (unsigned short*)(ws);            // 16,777,216 B
  unsigned short* h4T       = (unsigned short*)(ws);            // overlays Xb (used after gemm)
  unsigned short* Wc        = (unsigned short*)(ws + 16777216); //  6,553,600 B
  float*          bc        = (float*)(ws + 23330816);          //     12,800 B
  float*          stats_col = (float*)(ws + 23343616);          //     25,600 B
  unsigned short* h2T       = (unsigned short*)(ws + 23369344); // 52,428,800 B

  k_prep<<<4884, 256, 0, stream>>>(x, Xb, stats_col, fc_w, fc_b, conv_w, conv_b, Wc, bc);
  k_gemm<<<1600, 256, 0, stream>>>(Xb, Wc, bc, h2T, stats_col);
  k_tail1<<<dim3(32, 13), 256, 0, stream>>>(h2T, stats_col, gamma, beta, lw1, h4T);
  k_tail2<<<dim3(128, 3), 256, 0, stream>>>(h4T, lw2, (float*)d_out);
}

// Round 5
// 471.551 us; speedup vs baseline: 1.4261x; 1.4261x over previous
//
#include <hip/hip_runtime.h>

// ---------------------------------------------------------------------------
// Generator head, fused:
//   FC(1024->7056) + Conv2x2'same' folded into one bf16 GEMM
//   (M=8192, N=3136 pad 3200, K=1024, BK=32), K-loop = register-prefetch +
//   LDS double-buffer pipeline with MANUALLY UNROLLED even/odd bodies and
//   scalar uint4 prefetch registers (R4's dynamic-indexed arrays spilled to
//   scratch: WRITE_SIZE 879 MB). Epilogue: +bias, LeakyReLU, bf16 store
//   transposed (h2T[n][m]) + fused per-column BN stats. Then BN-apply +
//   local conv1 (inline BN reduce) and local conv2, batch-per-lane.
// ---------------------------------------------------------------------------

#define SLOPE 0.01f

typedef __bf16 bf16x8 __attribute__((ext_vector_type(8)));
typedef float f32x4 __attribute__((ext_vector_type(4)));

__device__ __forceinline__ unsigned short f2bf(float f) {
  union { float f; unsigned int u; } v; v.f = f;
  unsigned int r = v.u + 0x7FFFu + ((v.u >> 16) & 1u);
  return (unsigned short)(r >> 16);
}
__device__ __forceinline__ float bfbits2f(unsigned int bits16) {
  union { unsigned int u; float f; } v; v.u = bits16 << 16;
  return v.f;
}
__device__ __forceinline__ float leaky(float v) { return v >= 0.f ? v : SLOPE * v; }

// ---------------- K0: fused cast-x + weight-fold (one dispatch) ------------
__global__ void k_prep(const float* __restrict__ x, unsigned short* __restrict__ xb,
                       float* __restrict__ stats_col,
                       const float* __restrict__ fc_w, const float* __restrict__ fc_b,
                       const float* __restrict__ conv_w, const float* __restrict__ conv_b,
                       unsigned short* __restrict__ Wc, float* __restrict__ bc) {
  const int t = threadIdx.x;
  if (blockIdx.x < 4096) {
    if (blockIdx.x == 0)
      for (int i = t; i < 6400; i += 256) stats_col[i] = 0.f;
    int gid = blockIdx.x * 256 + t;
    const float4* x4 = (const float4*)x;
    float4 a = x4[gid * 2], b = x4[gid * 2 + 1];
    union { unsigned short s[8]; uint4 v; } o;
    o.s[0] = f2bf(a.x); o.s[1] = f2bf(a.y); o.s[2] = f2bf(a.z); o.s[3] = f2bf(a.w);
    o.s[4] = f2bf(b.x); o.s[5] = f2bf(b.y); o.s[6] = f2bf(b.z); o.s[7] = f2bf(b.w);
    ((uint4*)xb)[gid] = o.v;
    return;
  }
  int bid = blockIdx.x - 4096;          // 0..787
  int kq = bid & 3, blk = bid >> 2;     // 4 k-quarters x 197
  if (blk == 196) {                     // zero pad rows [3136,3200)
    uint4 z = make_uint4(0, 0, 0, 0);
    for (int i = t; i < 64 * 32; i += 256) {
      int r = i >> 5, qq = i & 31;
      *(uint4*)(Wc + (3136 + r) * 1024 + kq * 256 + qq * 8) = z;
    }
    if (kq == 0) for (int i = 3136 + t; i < 3200; i += 256) bc[i] = 0.f;
    return;
  }
  __shared__ float cw[2304];  // 16*36*2*2
  for (int i = t; i < 2304; i += 256) cw[i] = conv_w[i];
  __syncthreads();
  int i0 = blk / 14, j0 = blk - (blk / 14) * 14;
  int k = kq * 256 + t;
  float acc[16];
#pragma unroll
  for (int o = 0; o < 16; o++) acc[o] = 0.f;
  for (int c = 0; c < 36; c++) {
#pragma unroll
    for (int dy = 0; dy < 2; dy++) {
      int ii = i0 + dy; if (ii > 13) continue;
#pragma unroll
      for (int dx = 0; dx < 2; dx++) {
        int jj = j0 + dx; if (jj > 13) continue;
        float f = fc_w[((ii * 14 + jj) * 36 + c) * 1024 + k];
        int kk = dy * 2 + dx;
#pragma unroll
        for (int o = 0; o < 16; o++) acc[o] += cw[(o * 36 + c) * 4 + kk] * f;
      }
    }
  }
#pragma unroll
  for (int o = 0; o < 16; o++)
    Wc[(o * 196 + i0 * 14 + j0) * 1024 + k] = f2bf(acc[o]);
  if (kq == 0 && t < 16) {
    int o = t;
    float b = conv_b[o];
    for (int c = 0; c < 36; c++)
      for (int dy = 0; dy < 2; dy++) {
        int ii = i0 + dy; if (ii > 13) continue;
        for (int dx = 0; dx < 2; dx++) {
          int jj = j0 + dx; if (jj > 13) continue;
          b += cw[(o * 36 + c) * 4 + dy * 2 + dx] * fc_b[(ii * 14 + jj) * 36 + c];
        }
      }
    bc[o * 196 + i0 * 14 + j0] = b;
  }
}

// ------------- K2: bf16 MFMA GEMM, reg-prefetch + LDS double-buffer --------
// Even/odd manually-unrolled bodies; prefetch regs are named scalars (no
// dynamic indexing -> no scratch). Set A stages even k-steps, set B odd.
// Body(j): ds_read frags from buf[j&1]; issue loads for j+2; 16 MFMA;
// ds_write set for j+1 into buf[(j+1)&1]; barrier.
__global__ __launch_bounds__(256, 3) void k_gemm(const unsigned short* __restrict__ Xb,
                                                 const unsigned short* __restrict__ Wcb,
                                                 const float* __restrict__ bc,
                                                 unsigned short* __restrict__ h2,
                                                 float* __restrict__ stats_col) {
  __shared__ __align__(16) char lds[32768];  // buf0 [0,16K): A 8K | B 8K; buf1 [16K,32K)
  const int t = threadIdx.x;
  const int w = t >> 6, lane = t & 63;
  const int quad = lane >> 4, l15 = lane & 15;
  const int lid = blockIdx.x;
  const int m0 = (lid & 63) * 128, n0 = (lid >> 6) * 128;  // y-major (XCD A-banding)
  const int mrow = t & 127, tko = t >> 7;
  const unsigned short* ga = Xb + (m0 + mrow) * 1024 + tko * 8;
  const unsigned short* gb = Wcb + (n0 + mrow) * 1024 + tko * 8;
  char* const w0 = lds + tko * 2048 + mrow * 16;           // slot tko in buf0
  char* const w1 = w0 + 16384;                             // slot tko in buf1
  const int wm0 = (w >> 1) * 64, wn0 = (w & 1) * 64;

  f32x4 acc[4][4];
#pragma unroll
  for (int a = 0; a < 4; a++)
#pragma unroll
    for (int b = 0; b < 4; b++) acc[a][b] = (f32x4){0.f, 0.f, 0.f, 0.f};

  // prefetch register sets: A = even steps, B = odd steps (all named scalars)
  uint4 pa0, pa1, pb0, pb1;   // set A
  uint4 qa0, qa1, qb0, qb1;   // set B

  // k-step 0 -> set A -> buf0
  pa0 = *(const uint4*)(ga);      pa1 = *(const uint4*)(ga + 16);
  pb0 = *(const uint4*)(gb);      pb1 = *(const uint4*)(gb + 16);
  *(uint4*)(w0)         = pa0;  *(uint4*)(w0 + 4096)  = pa1;
  *(uint4*)(w0 + 8192)  = pb0;  *(uint4*)(w0 + 12288) = pb1;
  // k-step 1 -> set B
  qa0 = *(const uint4*)(ga + 32); qa1 = *(const uint4*)(ga + 48);
  qb0 = *(const uint4*)(gb + 32); qb1 = *(const uint4*)(gb + 48);
  __syncthreads();

  for (int jj = 0; jj < 16; jj++) {
    // ---- even step j = 2*jj: read buf0, prefetch j+2 -> set A, write B->buf1
    {
      bf16x8 af0, af1, af2, af3, bf0, bf1_, bf2, bf3;
      const char* rb = lds + quad * 2048;
      af0 = *(const bf16x8*)(rb + (wm0 + l15) * 16);
      af1 = *(const bf16x8*)(rb + (wm0 + 16 + l15) * 16);
      af2 = *(const bf16x8*)(rb + (wm0 + 32 + l15) * 16);
      af3 = *(const bf16x8*)(rb + (wm0 + 48 + l15) * 16);
      bf0 = *(const bf16x8*)(rb + 8192 + (wn0 + l15) * 16);
      bf1_ = *(const bf16x8*)(rb + 8192 + (wn0 + 16 + l15) * 16);
      bf2 = *(const bf16x8*)(rb + 8192 + (wn0 + 32 + l15) * 16);
      bf3 = *(const bf16x8*)(rb + 8192 + (wn0 + 48 + l15) * 16);
      const int off = (2 * jj + 2) * 32;   // overruns K on jj=15: in-ws, unused
      pa0 = *(const uint4*)(ga + off);      pa1 = *(const uint4*)(ga + off + 16);
      pb0 = *(const uint4*)(gb + off);      pb1 = *(const uint4*)(gb + off + 16);
      acc[0][0] = __builtin_amdgcn_mfma_f32_16x16x32_bf16(af0, bf0, acc[0][0], 0, 0, 0);
      acc[0][1] = __builtin_amdgcn_mfma_f32_16x16x32_bf16(af0, bf1_, acc[0][1], 0, 0, 0);
      acc[0][2] = __builtin_amdgcn_mfma_f32_16x16x32_bf16(af0, bf2, acc[0][2], 0, 0, 0);
      acc[0][3] = __builtin_amdgcn_mfma_f32_16x16x32_bf16(af0, bf3, acc[0][3], 0, 0, 0);
      acc[1][0] = __builtin_amdgcn_mfma_f32_16x16x32_bf16(af1, bf0, acc[1][0], 0, 0, 0);
      acc[1][1] = __builtin_amdgcn_mfma_f32_16x16x32_bf16(af1, bf1_, acc[1][1], 0, 0, 0);
      acc[1][2] = __builtin_amdgcn_mfma_f32_16x16x32_bf16(af1, bf2, acc[1][2], 0, 0, 0);
      acc[1][3] = __builtin_amdgcn_mfma_f32_16x16x32_bf16(af1, bf3, acc[1][3], 0, 0, 0);
      acc[2][0] = __builtin_amdgcn_mfma_f32_16x16x32_bf16(af2, bf0, acc[2][0], 0, 0, 0);
      acc[2][1] = __builtin_amdgcn_mfma_f32_16x16x32_bf16(af2, bf1_, acc[2][1], 0, 0, 0);
      acc[2][2] = __builtin_amdgcn_mfma_f32_16x16x32_bf16(af2, bf2, acc[2][2], 0, 0, 0);
      acc[2][3] = __builtin_amdgcn_mfma_f32_16x16x32_bf16(af2, bf3, acc[2][3], 0, 0, 0);
      acc[3][0] = __builtin_amdgcn_mfma_f32_16x16x32_bf16(af3, bf0, acc[3][0], 0, 0, 0);
      acc[3][1] = __builtin_amdgcn_mfma_f32_16x16x32_bf16(af3, bf1_, acc[3][1], 0, 0, 0);
      acc[3][2] = __builtin_amdgcn_mfma_f32_16x16x32_bf16(af3, bf2, acc[3][2], 0, 0, 0);
      acc[3][3] = __builtin_amdgcn_mfma_f32_16x16x32_bf16(af3, bf3, acc[3][3], 0, 0, 0);
      *(uint4*)(w1)         = qa0;  *(uint4*)(w1 + 4096)  = qa1;
      *(uint4*)(w1 + 8192)  = qb0;  *(uint4*)(w1 + 12288) = qb1;
      __syncthreads();
    }
    // ---- odd step j = 2*jj+1: read buf1, prefetch j+2 -> set B, write A->buf0
    {
      bf16x8 af0, af1, af2, af3, bf0, bf1_, bf2, bf3;
      const char* rb = lds + 16384 + quad * 2048;
      af0 = *(const bf16x8*)(rb + (wm0 + l15) * 16);
      af1 = *(const bf16x8*)(rb + (wm0 + 16 + l15) * 16);
      af2 = *(const bf16x8*)(rb + (wm0 + 32 + l15) * 16);
      af3 = *(const bf16x8*)(rb + (wm0 + 48 + l15) * 16);
      bf0 = *(const bf16x8*)(rb + 8192 + (wn0 + l15) * 16);
      bf1_ = *(const bf16x8*)(rb + 8192 + (wn0 + 16 + l15) * 16);
      bf2 = *(const bf16x8*)(rb + 8192 + (wn0 + 32 + l15) * 16);
      bf3 = *(const bf16x8*)(rb + 8192 + (wn0 + 48 + l15) * 16);
      const int off = (2 * jj + 3) * 32;
      qa0 = *(const uint4*)(ga + off);      qa1 = *(const uint4*)(ga + off + 16);
      qb0 = *(const uint4*)(gb + off);      qb1 = *(const uint4*)(gb + off + 16);
      acc[0][0] = __builtin_amdgcn_mfma_f32_16x16x32_bf16(af0, bf0, acc[0][0], 0, 0, 0);
      acc[0][1] = __builtin_amdgcn_mfma_f32_16x16x32_bf16(af0, bf1_, acc[0][1], 0, 0, 0);
      acc[0][2] = __builtin_amdgcn_mfma_f32_16x16x32_bf16(af0, bf2, acc[0][2], 0, 0, 0);
      acc[0][3] = __builtin_amdgcn_mfma_f32_16x16x32_bf16(af0, bf3, acc[0][3], 0, 0, 0);
      acc[1][0] = __builtin_amdgcn_mfma_f32_16x16x32_bf16(af1, bf0, acc[1][0], 0, 0, 0);
      acc[1][1] = __builtin_amdgcn_mfma_f32_16x16x32_bf16(af1, bf1_, acc[1][1], 0, 0, 0);
      acc[1][2] = __builtin_amdgcn_mfma_f32_16x16x32_bf16(af1, bf2, acc[1][2], 0, 0, 0);
      acc[1][3] = __builtin_amdgcn_mfma_f32_16x16x32_bf16(af1, bf3, acc[1][3], 0, 0, 0);
      acc[2][0] = __builtin_amdgcn_mfma_f32_16x16x32_bf16(af2, bf0, acc[2][0], 0, 0, 0);
      acc[2][1] = __builtin_amdgcn_mfma_f32_16x16x32_bf16(af2, bf1_, acc[2][1], 0, 0, 0);
      acc[2][2] = __builtin_amdgcn_mfma_f32_16x16x32_bf16(af2, bf2, acc[2][2], 0, 0, 0);
      acc[2][3] = __builtin_amdgcn_mfma_f32_16x16x32_bf16(af2, bf3, acc[2][3], 0, 0, 0);
      acc[3][0] = __builtin_amdgcn_mfma_f32_16x16x32_bf16(af3, bf0, acc[3][0], 0, 0, 0);
      acc[3][1] = __builtin_amdgcn_mfma_f32_16x16x32_bf16(af3, bf1_, acc[3][1], 0, 0, 0);
      acc[3][2] = __builtin_amdgcn_mfma_f32_16x16x32_bf16(af3, bf2, acc[3][2], 0, 0, 0);
      acc[3][3] = __builtin_amdgcn_mfma_f32_16x16x32_bf16(af3, bf3, acc[3][3], 0, 0, 0);
      *(uint4*)(w0)         = pa0;  *(uint4*)(w0 + 4096)  = pa1;
      *(uint4*)(w0 + 8192)  = pb0;  *(uint4*)(w0 + 12288) = pb1;
      __syncthreads();
    }
  }

#pragma unroll
  for (int nb = 0; nb < 4; nb++) {
    int col = n0 + wn0 + nb * 16 + l15;
    float bias = bc[col];
    float s = 0.f, s2 = 0.f;
    unsigned short* base = h2 + col * 8192 + m0 + wm0 + quad * 4;
#pragma unroll
    for (int mb = 0; mb < 4; mb++) {
      union { unsigned short u[4]; uint2 v; } pk;
#pragma unroll
      for (int r = 0; r < 4; r++) {
        float v = leaky(acc[mb][nb][r] + bias);   // C/D: row=(lane>>4)*4+reg, col=lane&15
        s += v; s2 += v * v;
        pk.u[r] = f2bf(v);
      }
      *(uint2*)(base + mb * 16) = pk.v;           // 8B store, m-contiguous
    }
    s  += __shfl_xor(s, 16, 64);  s  += __shfl_xor(s, 32, 64);
    s2 += __shfl_xor(s2, 16, 64); s2 += __shfl_xor(s2, 32, 64);
    if (quad == 0) {
      atomicAdd(&stats_col[col], s);
      atomicAdd(&stats_col[3200 + col], s2);
    }
  }
}

// -------- K3: BN scale reduce (inline) + BN-apply + local conv1 + leaky ----
__global__ __launch_bounds__(256) void k_tail1(const unsigned short* __restrict__ h2,
                                               const float* __restrict__ stats_col,
                                               const float* __restrict__ gamma,
                                               const float* __restrict__ beta,
                                               const float* __restrict__ lw1,
                                               unsigned short* __restrict__ h4) {
  __shared__ float chs[32];
  __shared__ float sc_s[16], sh_s[16];
  const int t = threadIdx.x;
  if (t < 32) chs[t] = 0.f;
  __syncthreads();
  for (int col = t; col < 3136; col += 256) {
    int o = col / 196;
    atomicAdd(&chs[o], stats_col[col]);
    atomicAdd(&chs[16 + o], stats_col[3200 + col]);
  }
  __syncthreads();
  if (t < 16) {
    const float inv = 1.f / 1605632.f;  // 8192*196
    float mean = chs[t] * inv;
    float var = chs[16 + t] * inv - mean * mean;
    float sc = gamma[t] * rsqrtf(var + 1e-5f);
    sc_s[t] = sc; sh_s[t] = beta[t] - mean * sc;
  }
  __syncthreads();

  const int m = blockIdx.x * 256 + t;
  const int y = blockIdx.y;                     // 0..12
  float acc[6][13];
#pragma unroll
  for (int o = 0; o < 6; o++)
#pragma unroll
    for (int x = 0; x < 13; x++) acc[o][x] = 0.f;

  for (int c = 0; c < 16; c++) {
    float scc = sc_s[c], shc = sh_s[c];
    const unsigned short* p0 = h2 + (c * 196 + y * 14) * 8192 + m;
    float r0[14], r1[14];
#pragma unroll
    for (int x = 0; x < 14; x++) {
      r0[x] = bfbits2f(p0[x * 8192]) * scc + shc;
      r1[x] = bfbits2f(p0[(14 + x) * 8192]) * scc + shc;
    }
#pragma unroll
    for (int o = 0; o < 6; o++) {
      const float* wp = lw1 + (((o * 16 + c) * 13 + y) * 13) * 4;  // uniform -> s_load
#pragma unroll
      for (int x = 0; x < 13; x++)
        acc[o][x] += r0[x] * wp[4 * x] + r0[x + 1] * wp[4 * x + 1] +
                     r1[x] * wp[4 * x + 2] + r1[x + 1] * wp[4 * x + 3];
    }
  }
  unsigned short* q = h4 + y * 13 * 8192 + m;   // row (o*13+y)*13+x
#pragma unroll
  for (int o = 0; o < 6; o++)
#pragma unroll
    for (int x = 0; x < 13; x++)
      q[(o * 169 + x) * 8192] = f2bf(leaky(acc[o][x]));
}

// ------------------------- K4: local conv2 (batch-per-lane) ----------------
__global__ __launch_bounds__(256) void k_tail2(const unsigned short* __restrict__ h4,
                                               const float* __restrict__ lw2,
                                               float* __restrict__ out) {
  const int lane = threadIdx.x & 63, w = threadIdx.x >> 6;
  const int m = blockIdx.x * 64 + lane;
  const int y = blockIdx.y * 4 + w;             // 0..11
  float acc[12];
#pragma unroll
  for (int x = 0; x < 12; x++) acc[x] = 0.f;
  for (int c = 0; c < 6; c++) {
    const unsigned short* p = h4 + (c * 13 + y) * 13 * 8192 + m;
    float r0[13], r1[13];
#pragma unroll
    for (int x = 0; x < 13; x++) {
      r0[x] = bfbits2f(p[x * 8192]);
      r1[x] = bfbits2f(p[(13 + x) * 8192]);
    }
    const float* wp = lw2 + ((c * 12 + y) * 12) * 4;  // uniform -> s_load
#pragma unroll
    for (int x = 0; x < 12; x++)
      acc[x] += r0[x] * wp[4 * x] + r0[x + 1] * wp[4 * x + 1] +
                r1[x] * wp[4 * x + 2] + r1[x + 1] * wp[4 * x + 3];
  }
  float* op = out + m * 144 + y * 12;
#pragma unroll
  for (int x = 0; x < 12; x++) op[x] = acc[x];
}

// ---------------------------------------------------------------------------
extern "C" void kernel_launch(void* const* d_in, const int* in_sizes, int n_in,
                              void* d_out, int out_size, void* d_ws, size_t ws_size,
                              hipStream_t stream) {
  const float* x      = (const float*)d_in[0];
  const float* fc_w   = (const float*)d_in[1];
  const float* fc_b   = (const float*)d_in[2];
  const float* conv_w = (const float*)d_in[3];
  const float* conv_b = (const float*)d_in[4];
  const float* gamma  = (const float*)d_in[5];
  const float* beta   = (const float*)d_in[6];
  const float* lw1    = (const float*)d_in[7];
  const float* lw2    = (const float*)d_in[8];

  char* ws = (char*)d_ws;
  // workspace layout (75.8 MB total)
  unsigned short* Xb        = (unsigned short*)(ws);            // 16,777,216 B
  unsigned short* h4T       = (unsigned short*)(ws);            // overlays Xb (used after gemm)
  unsigned short* Wc        = (unsigned short*)(ws + 16777216); //  6,553,600 B
  float*          bc        = (float*)(ws + 23330816);          //     12,800 B
  float*          stats_col = (float*)(ws + 23343616);          //     25,600 B
  unsigned short* h2T       = (unsigned short*)(ws + 23369344); // 52,428,800 B

  k_prep<<<4884, 256, 0, stream>>>(x, Xb, stats_col, fc_w, fc_b, conv_w, conv_b, Wc, bc);
  k_gemm<<<1600, 256, 0, stream>>>(Xb, Wc, bc, h2T, stats_col);
  k_tail1<<<dim3(32, 13), 256, 0, stream>>>(h2T, stats_col, gamma, beta, lw1, h4T);
  k_tail2<<<dim3(128, 3), 256, 0, stream>>>(h4T, lw2, (float*)d_out);
}

// Round 6
// 466.730 us; speedup vs baseline: 1.4409x; 1.0103x over previous
//
#include <hip/hip_runtime.h>

// ---------------------------------------------------------------------------
// Generator head, fused:
//   FC(1024->7056) + Conv2x2'same' folded into one bf16 GEMM
//   (M=8192, N=3136 pad 3200, K=1024, BK=32), K-loop = register-prefetch +
//   LDS double-buffer pipeline (manually unrolled even/odd bodies, scalar
//   uint4 prefetch regs). R6: super-tile swizzle -- XCD x owns m-tiles
//   [8x,8x+8) (A band 2MB L2-resident) and sweeps n-strips slowly (B strip
//   256KB fetched once per XCD into L2), so staging runs at XCD-L2 BW
//   instead of streaming B from L3 every iteration. launch_bounds(256,4).
// ---------------------------------------------------------------------------

#define SLOPE 0.01f

typedef __bf16 bf16x8 __attribute__((ext_vector_type(8)));
typedef float f32x4 __attribute__((ext_vector_type(4)));

__device__ __forceinline__ unsigned short f2bf(float f) {
  union { float f; unsigned int u; } v; v.f = f;
  unsigned int r = v.u + 0x7FFFu + ((v.u >> 16) & 1u);
  return (unsigned short)(r >> 16);
}
__device__ __forceinline__ float bfbits2f(unsigned int bits16) {
  union { unsigned int u; float f; } v; v.u = bits16 << 16;
  return v.f;
}
__device__ __forceinline__ float leaky(float v) { return v >= 0.f ? v : SLOPE * v; }

// ---------------- K0: fused cast-x + weight-fold (one dispatch) ------------
__global__ void k_prep(const float* __restrict__ x, unsigned short* __restrict__ xb,
                       float* __restrict__ stats_col,
                       const float* __restrict__ fc_w, const float* __restrict__ fc_b,
                       const float* __restrict__ conv_w, const float* __restrict__ conv_b,
                       unsigned short* __restrict__ Wc, float* __restrict__ bc) {
  const int t = threadIdx.x;
  if (blockIdx.x < 4096) {
    if (blockIdx.x == 0)
      for (int i = t; i < 6400; i += 256) stats_col[i] = 0.f;
    int gid = blockIdx.x * 256 + t;
    const float4* x4 = (const float4*)x;
    float4 a = x4[gid * 2], b = x4[gid * 2 + 1];
    union { unsigned short s[8]; uint4 v; } o;
    o.s[0] = f2bf(a.x); o.s[1] = f2bf(a.y); o.s[2] = f2bf(a.z); o.s[3] = f2bf(a.w);
    o.s[4] = f2bf(b.x); o.s[5] = f2bf(b.y); o.s[6] = f2bf(b.z); o.s[7] = f2bf(b.w);
    ((uint4*)xb)[gid] = o.v;
    return;
  }
  int bid = blockIdx.x - 4096;          // 0..787
  int kq = bid & 3, blk = bid >> 2;     // 4 k-quarters x 197
  if (blk == 196) {                     // zero pad rows [3136,3200)
    uint4 z = make_uint4(0, 0, 0, 0);
    for (int i = t; i < 64 * 32; i += 256) {
      int r = i >> 5, qq = i & 31;
      *(uint4*)(Wc + (3136 + r) * 1024 + kq * 256 + qq * 8) = z;
    }
    if (kq == 0) for (int i = 3136 + t; i < 3200; i += 256) bc[i] = 0.f;
    return;
  }
  __shared__ float cw[2304];  // 16*36*2*2
  for (int i = t; i < 2304; i += 256) cw[i] = conv_w[i];
  __syncthreads();
  int i0 = blk / 14, j0 = blk - (blk / 14) * 14;
  int k = kq * 256 + t;
  float acc[16];
#pragma unroll
  for (int o = 0; o < 16; o++) acc[o] = 0.f;
  for (int c = 0; c < 36; c++) {
#pragma unroll
    for (int dy = 0; dy < 2; dy++) {
      int ii = i0 + dy; if (ii > 13) continue;
#pragma unroll
      for (int dx = 0; dx < 2; dx++) {
        int jj = j0 + dx; if (jj > 13) continue;
        float f = fc_w[((ii * 14 + jj) * 36 + c) * 1024 + k];
        int kk = dy * 2 + dx;
#pragma unroll
        for (int o = 0; o < 16; o++) acc[o] += cw[(o * 36 + c) * 4 + kk] * f;
      }
    }
  }
#pragma unroll
  for (int o = 0; o < 16; o++)
    Wc[(o * 196 + i0 * 14 + j0) * 1024 + k] = f2bf(acc[o]);
  if (kq == 0 && t < 16) {
    int o = t;
    float b = conv_b[o];
    for (int c = 0; c < 36; c++)
      for (int dy = 0; dy < 2; dy++) {
        int ii = i0 + dy; if (ii > 13) continue;
        for (int dx = 0; dx < 2; dx++) {
          int jj = j0 + dx; if (jj > 13) continue;
          b += cw[(o * 36 + c) * 4 + dy * 2 + dx] * fc_b[(ii * 14 + jj) * 36 + c];
        }
      }
    bc[o * 196 + i0 * 14 + j0] = b;
  }
}

// ------------- K2: bf16 MFMA GEMM, reg-prefetch + LDS double-buffer --------
// Super-tile swizzle: x = lid&7 (XCD under round-robin dispatch), k = lid>>3;
// m_tile = x*8 + (k&7)  -> XCD-fixed 8-tile A band (2 MB, L2-resident)
// n_strip = k>>3        -> changes every 8 blocks; 256 KB B strip fetched
//                          once per XCD into L2, then re-read from L2.
__global__ __launch_bounds__(256, 4) void k_gemm(const unsigned short* __restrict__ Xb,
                                                 const unsigned short* __restrict__ Wcb,
                                                 const float* __restrict__ bc,
                                                 unsigned short* __restrict__ h2,
                                                 float* __restrict__ stats_col) {
  __shared__ __align__(16) char lds[32768];  // buf0 [0,16K): A 8K | B 8K; buf1 [16K,32K)
  const int t = threadIdx.x;
  const int w = t >> 6, lane = t & 63;
  const int quad = lane >> 4, l15 = lane & 15;
  const int lid = blockIdx.x;
  const int xcd = lid & 7, kk = lid >> 3;
  const int m0 = (xcd * 8 + (kk & 7)) * 128, n0 = (kk >> 3) * 128;
  const int mrow = t & 127, tko = t >> 7;
  const unsigned short* ga = Xb + (m0 + mrow) * 1024 + tko * 8;
  const unsigned short* gb = Wcb + (n0 + mrow) * 1024 + tko * 8;
  char* const w0 = lds + tko * 2048 + mrow * 16;           // slot tko in buf0
  char* const w1 = w0 + 16384;                             // slot tko in buf1
  const int wm0 = (w >> 1) * 64, wn0 = (w & 1) * 64;

  f32x4 acc[4][4];
#pragma unroll
  for (int a = 0; a < 4; a++)
#pragma unroll
    for (int b = 0; b < 4; b++) acc[a][b] = (f32x4){0.f, 0.f, 0.f, 0.f};

  // prefetch register sets: A = even steps, B = odd steps (all named scalars)
  uint4 pa0, pa1, pb0, pb1;   // set A
  uint4 qa0, qa1, qb0, qb1;   // set B

  // k-step 0 -> set A -> buf0
  pa0 = *(const uint4*)(ga);      pa1 = *(const uint4*)(ga + 16);
  pb0 = *(const uint4*)(gb);      pb1 = *(const uint4*)(gb + 16);
  *(uint4*)(w0)         = pa0;  *(uint4*)(w0 + 4096)  = pa1;
  *(uint4*)(w0 + 8192)  = pb0;  *(uint4*)(w0 + 12288) = pb1;
  // k-step 1 -> set B
  qa0 = *(const uint4*)(ga + 32); qa1 = *(const uint4*)(ga + 48);
  qb0 = *(const uint4*)(gb + 32); qb1 = *(const uint4*)(gb + 48);
  __syncthreads();

  for (int jj = 0; jj < 16; jj++) {
    // ---- even step j = 2*jj: read buf0, prefetch j+2 -> set A, write B->buf1
    {
      bf16x8 af0, af1, af2, af3, bf0, bf1_, bf2, bf3;
      const char* rb = lds + quad * 2048;
      af0 = *(const bf16x8*)(rb + (wm0 + l15) * 16);
      af1 = *(const bf16x8*)(rb + (wm0 + 16 + l15) * 16);
      af2 = *(const bf16x8*)(rb + (wm0 + 32 + l15) * 16);
      af3 = *(const bf16x8*)(rb + (wm0 + 48 + l15) * 16);
      bf0 = *(const bf16x8*)(rb + 8192 + (wn0 + l15) * 16);
      bf1_ = *(const bf16x8*)(rb + 8192 + (wn0 + 16 + l15) * 16);
      bf2 = *(const bf16x8*)(rb + 8192 + (wn0 + 32 + l15) * 16);
      bf3 = *(const bf16x8*)(rb + 8192 + (wn0 + 48 + l15) * 16);
      const int off = (2 * jj + 2) * 32;   // overruns K on jj=15: in-ws, unused
      pa0 = *(const uint4*)(ga + off);      pa1 = *(const uint4*)(ga + off + 16);
      pb0 = *(const uint4*)(gb + off);      pb1 = *(const uint4*)(gb + off + 16);
      acc[0][0] = __builtin_amdgcn_mfma_f32_16x16x32_bf16(af0, bf0, acc[0][0], 0, 0, 0);
      acc[0][1] = __builtin_amdgcn_mfma_f32_16x16x32_bf16(af0, bf1_, acc[0][1], 0, 0, 0);
      acc[0][2] = __builtin_amdgcn_mfma_f32_16x16x32_bf16(af0, bf2, acc[0][2], 0, 0, 0);
      acc[0][3] = __builtin_amdgcn_mfma_f32_16x16x32_bf16(af0, bf3, acc[0][3], 0, 0, 0);
      acc[1][0] = __builtin_amdgcn_mfma_f32_16x16x32_bf16(af1, bf0, acc[1][0], 0, 0, 0);
      acc[1][1] = __builtin_amdgcn_mfma_f32_16x16x32_bf16(af1, bf1_, acc[1][1], 0, 0, 0);
      acc[1][2] = __builtin_amdgcn_mfma_f32_16x16x32_bf16(af1, bf2, acc[1][2], 0, 0, 0);
      acc[1][3] = __builtin_amdgcn_mfma_f32_16x16x32_bf16(af1, bf3, acc[1][3], 0, 0, 0);
      acc[2][0] = __builtin_amdgcn_mfma_f32_16x16x32_bf16(af2, bf0, acc[2][0], 0, 0, 0);
      acc[2][1] = __builtin_amdgcn_mfma_f32_16x16x32_bf16(af2, bf1_, acc[2][1], 0, 0, 0);
      acc[2][2] = __builtin_amdgcn_mfma_f32_16x16x32_bf16(af2, bf2, acc[2][2], 0, 0, 0);
      acc[2][3] = __builtin_amdgcn_mfma_f32_16x16x32_bf16(af2, bf3, acc[2][3], 0, 0, 0);
      acc[3][0] = __builtin_amdgcn_mfma_f32_16x16x32_bf16(af3, bf0, acc[3][0], 0, 0, 0);
      acc[3][1] = __builtin_amdgcn_mfma_f32_16x16x32_bf16(af3, bf1_, acc[3][1], 0, 0, 0);
      acc[3][2] = __builtin_amdgcn_mfma_f32_16x16x32_bf16(af3, bf2, acc[3][2], 0, 0, 0);
      acc[3][3] = __builtin_amdgcn_mfma_f32_16x16x32_bf16(af3, bf3, acc[3][3], 0, 0, 0);
      *(uint4*)(w1)         = qa0;  *(uint4*)(w1 + 4096)  = qa1;
      *(uint4*)(w1 + 8192)  = qb0;  *(uint4*)(w1 + 12288) = qb1;
      __syncthreads();
    }
    // ---- odd step j = 2*jj+1: read buf1, prefetch j+2 -> set B, write A->buf0
    {
      bf16x8 af0, af1, af2, af3, bf0, bf1_, bf2, bf3;
      const char* rb = lds + 16384 + quad * 2048;
      af0 = *(const bf16x8*)(rb + (wm0 + l15) * 16);
      af1 = *(const bf16x8*)(rb + (wm0 + 16 + l15) * 16);
      af2 = *(const bf16x8*)(rb + (wm0 + 32 + l15) * 16);
      af3 = *(const bf16x8*)(rb + (wm0 + 48 + l15) * 16);
      bf0 = *(const bf16x8*)(rb + 8192 + (wn0 + l15) * 16);
      bf1_ = *(const bf16x8*)(rb + 8192 + (wn0 + 16 + l15) * 16);
      bf2 = *(const bf16x8*)(rb + 8192 + (wn0 + 32 + l15) * 16);
      bf3 = *(const bf16x8*)(rb + 8192 + (wn0 + 48 + l15) * 16);
      const int off = (2 * jj + 3) * 32;
      qa0 = *(const uint4*)(ga + off);      qa1 = *(const uint4*)(ga + off + 16);
      qb0 = *(const uint4*)(gb + off);      qb1 = *(const uint4*)(gb + off + 16);
      acc[0][0] = __builtin_amdgcn_mfma_f32_16x16x32_bf16(af0, bf0, acc[0][0], 0, 0, 0);
      acc[0][1] = __builtin_amdgcn_mfma_f32_16x16x32_bf16(af0, bf1_, acc[0][1], 0, 0, 0);
      acc[0][2] = __builtin_amdgcn_mfma_f32_16x16x32_bf16(af0, bf2, acc[0][2], 0, 0, 0);
      acc[0][3] = __builtin_amdgcn_mfma_f32_16x16x32_bf16(af0, bf3, acc[0][3], 0, 0, 0);
      acc[1][0] = __builtin_amdgcn_mfma_f32_16x16x32_bf16(af1, bf0, acc[1][0], 0, 0, 0);
      acc[1][1] = __builtin_amdgcn_mfma_f32_16x16x32_bf16(af1, bf1_, acc[1][1], 0, 0, 0);
      acc[1][2] = __builtin_amdgcn_mfma_f32_16x16x32_bf16(af1, bf2, acc[1][2], 0, 0, 0);
      acc[1][3] = __builtin_amdgcn_mfma_f32_16x16x32_bf16(af1, bf3, acc[1][3], 0, 0, 0);
      acc[2][0] = __builtin_amdgcn_mfma_f32_16x16x32_bf16(af2, bf0, acc[2][0], 0, 0, 0);
      acc[2][1] = __builtin_amdgcn_mfma_f32_16x16x32_bf16(af2, bf1_, acc[2][1], 0, 0, 0);
      acc[2][2] = __builtin_amdgcn_mfma_f32_16x16x32_bf16(af2, bf2, acc[2][2], 0, 0, 0);
      acc[2][3] = __builtin_amdgcn_mfma_f32_16x16x32_bf16(af2, bf3, acc[2][3], 0, 0, 0);
      acc[3][0] = __builtin_amdgcn_mfma_f32_16x16x32_bf16(af3, bf0, acc[3][0], 0, 0, 0);
      acc[3][1] = __builtin_amdgcn_mfma_f32_16x16x32_bf16(af3, bf1_, acc[3][1], 0, 0, 0);
      acc[3][2] = __builtin_amdgcn_mfma_f32_16x16x32_bf16(af3, bf2, acc[3][2], 0, 0, 0);
      acc[3][3] = __builtin_amdgcn_mfma_f32_16x16x32_bf16(af3, bf3, acc[3][3], 0, 0, 0);
      *(uint4*)(w0)         = pa0;  *(uint4*)(w0 + 4096)  = pa1;
      *(uint4*)(w0 + 8192)  = pb0;  *(uint4*)(w0 + 12288) = pb1;
      __syncthreads();
    }
  }

#pragma unroll
  for (int nb = 0; nb < 4; nb++) {
    int col = n0 + wn0 + nb * 16 + l15;
    float bias = bc[col];
    float s = 0.f, s2 = 0.f;
    unsigned short* base = h2 + col * 8192 + m0 + wm0 + quad * 4;
#pragma unroll
    for (int mb = 0; mb < 4; mb++) {
      union { unsigned short u[4]; uint2 v; } pk;
#pragma unroll
      for (int r = 0; r < 4; r++) {
        float v = leaky(acc[mb][nb][r] + bias);   // C/D: row=(lane>>4)*4+reg, col=lane&15
        s += v; s2 += v * v;
        pk.u[r] = f2bf(v);
      }
      *(uint2*)(base + mb * 16) = pk.v;           // 8B store, m-contiguous
    }
    s  += __shfl_xor(s, 16, 64);  s  += __shfl_xor(s, 32, 64);
    s2 += __shfl_xor(s2, 16, 64); s2 += __shfl_xor(s2, 32, 64);
    if (quad == 0) {
      atomicAdd(&stats_col[col], s);
      atomicAdd(&stats_col[3200 + col], s2);
    }
  }
}

// -------- K3: BN scale reduce (inline) + BN-apply + local conv1 + leaky ----
__global__ __launch_bounds__(256) void k_tail1(const unsigned short* __restrict__ h2,
                                               const float* __restrict__ stats_col,
                                               const float* __restrict__ gamma,
                                               const float* __restrict__ beta,
                                               const float* __restrict__ lw1,
                                               unsigned short* __restrict__ h4) {
  __shared__ float chs[32];
  __shared__ float sc_s[16], sh_s[16];
  const int t = threadIdx.x;
  if (t < 32) chs[t] = 0.f;
  __syncthreads();
  for (int col = t; col < 3136; col += 256) {
    int o = col / 196;
    atomicAdd(&chs[o], stats_col[col]);
    atomicAdd(&chs[16 + o], stats_col[3200 + col]);
  }
  __syncthreads();
  if (t < 16) {
    const float inv = 1.f / 1605632.f;  // 8192*196
    float mean = chs[t] * inv;
    float var = chs[16 + t] * inv - mean * mean;
    float sc = gamma[t] * rsqrtf(var + 1e-5f);
    sc_s[t] = sc; sh_s[t] = beta[t] - mean * sc;
  }
  __syncthreads();

  const int m = blockIdx.x * 256 + t;
  const int y = blockIdx.y;                     // 0..12
  float acc[6][13];
#pragma unroll
  for (int o = 0; o < 6; o++)
#pragma unroll
    for (int x = 0; x < 13; x++) acc[o][x] = 0.f;

  for (int c = 0; c < 16; c++) {
    float scc = sc_s[c], shc = sh_s[c];
    const unsigned short* p0 = h2 + (c * 196 + y * 14) * 8192 + m;
    float r0[14], r1[14];
#pragma unroll
    for (int x = 0; x < 14; x++) {
      r0[x] = bfbits2f(p0[x * 8192]) * scc + shc;
      r1[x] = bfbits2f(p0[(14 + x) * 8192]) * scc + shc;
    }
#pragma unroll
    for (int o = 0; o < 6; o++) {
      const float* wp = lw1 + (((o * 16 + c) * 13 + y) * 13) * 4;  // uniform -> s_load
#pragma unroll
      for (int x = 0; x < 13; x++)
        acc[o][x] += r0[x] * wp[4 * x] + r0[x + 1] * wp[4 * x + 1] +
                     r1[x] * wp[4 * x + 2] + r1[x + 1] * wp[4 * x + 3];
    }
  }
  unsigned short* q = h4 + y * 13 * 8192 + m;   // row (o*13+y)*13+x
#pragma unroll
  for (int o = 0; o < 6; o++)
#pragma unroll
    for (int x = 0; x < 13; x++)
      q[(o * 169 + x) * 8192] = f2bf(leaky(acc[o][x]));
}

// ------------------------- K4: local conv2 (batch-per-lane) ----------------
__global__ __launch_bounds__(256) void k_tail2(const unsigned short* __restrict__ h4,
                                               const float* __restrict__ lw2,
                                               float* __restrict__ out) {
  const int lane = threadIdx.x & 63, w = threadIdx.x >> 6;
  const int m = blockIdx.x * 64 + lane;
  const int y = blockIdx.y * 4 + w;             // 0..11
  float acc[12];
#pragma unroll
  for (int x = 0; x < 12; x++) acc[x] = 0.f;
  for (int c = 0; c < 6; c++) {
    const unsigned short* p = h4 + (c * 13 + y) * 13 * 8192 + m;
    float r0[13], r1[13];
#pragma unroll
    for (int x = 0; x < 13; x++) {
      r0[x] = bfbits2f(p[x * 8192]);
      r1[x] = bfbits2f(p[(13 + x) * 8192]);
    }
    const float* wp = lw2 + ((c * 12 + y) * 12) * 4;  // uniform -> s_load
#pragma unroll
    for (int x = 0; x < 12; x++)
      acc[x] += r0[x] * wp[4 * x] + r0[x + 1] * wp[4 * x + 1] +
                r1[x] * wp[4 * x + 2] + r1[x + 1] * wp[4 * x + 3];
  }
  float* op = out + m * 144 + y * 12;
#pragma unroll
  for (int x = 0; x < 12; x++) op[x] = acc[x];
}

// ---------------------------------------------------------------------------
extern "C" void kernel_launch(void* const* d_in, const int* in_sizes, int n_in,
                              void* d_out, int out_size, void* d_ws, size_t ws_size,
                              hipStream_t stream) {
  const float* x      = (const float*)d_in[0];
  const float* fc_w   = (const float*)d_in[1];
  const float* fc_b   = (const float*)d_in[2];
  const float* conv_w = (const float*)d_in[3];
  const float* conv_b = (const float*)d_in[4];
  const float* gamma  = (const float*)d_in[5];
  const float* beta   = (const float*)d_in[6];
  const float* lw1    = (const float*)d_in[7];
  const float* lw2    = (const float*)d_in[8];

  char* ws = (char*)d_ws;
  // workspace layout (75.8 MB total)
  unsigned short* Xb        = (unsigned short*)(ws);            // 16,777,216 B
  unsigned short* h4T       = (unsigned short*)(ws);            // overlays Xb (used after gemm)
  unsigned short* Wc        = (unsigned short*)(ws + 16777216); //  6,553,600 B
  float*          bc        = (float*)(ws + 23330816);          //     12,800 B
  float*          stats_col = (float*)(ws + 23343616);          //     25,600 B
  unsigned short* h2T       = (unsigned short*)(ws + 23369344); // 52,428,800 B

  k_prep<<<4884, 256, 0, stream>>>(x, Xb, stats_col, fc_w, fc_b, conv_w, conv_b, Wc, bc);
  k_gemm<<<1600, 256, 0, stream>>>(Xb, Wc, bc, h2T, stats_col);
  k_tail1<<<dim3(32, 13), 256, 0, stream>>>(h2T, stats_col, gamma, beta, lw1, h4T);
  k_tail2<<<dim3(128, 3), 256, 0, stream>>>(h4T, lw2, (float*)d_out);
}